// Round 2
// baseline (274.014 us; speedup 1.0000x reference)
//
#include <hip/hip_runtime.h>

// Problem dims (fixed by reference)
#define BATCH  4096
#define IN_DIM 256
#define HID    512
#define STATES 16
#define NCOL   (HID * STATES)   // 8192

// Tiling
#define BM 128
#define BN 128
#define BK 64

typedef __attribute__((ext_vector_type(8))) short bf16x8;
typedef __attribute__((ext_vector_type(4))) float f32x4;

__device__ __forceinline__ ushort f2bf(float f) {
    // round-to-nearest-even f32 -> bf16
    uint u = __builtin_bit_cast(uint, f);
    u += 0x7FFFu + ((u >> 16) & 1u);
    return (ushort)(u >> 16);
}
__device__ __forceinline__ float bf2f(ushort h) {
    uint u = ((uint)h) << 16;
    return __builtin_bit_cast(float, u);
}
// XOR swizzle: byte ^= slot(row)<<4. slot = (row&7)^((row>>3)&7).
// Read side (b128, 16 lanes span 16 rows, k fixed): 8 slots hit 2x -> free.
// Write side (W transpose scatter): ~4-way instead of 32-way.
__device__ __forceinline__ int swz(int row, int byteoff) {
    return byteoff ^ ((((row & 7) ^ ((row >> 3) & 7))) << 4);
}
__device__ __forceinline__ float tanh_fast(float x) {
    // tanh(x) = 1 - 2/(exp(2x)+1); exp via exp2, rcp via v_rcp_f32
    float e = __builtin_amdgcn_exp2f(x * 2.8853900817779268f); // 2*log2(e)
    float r = __builtin_amdgcn_rcpf(e + 1.0f);
    return __builtin_fmaf(-2.0f, r, 1.0f);
}

__global__ __launch_bounds__(256) void mqc_mfma_kernel(
    const float* __restrict__ x,        // [BATCH, IN_DIM]
    const float* __restrict__ hq,       // [BATCH, NCOL]
    const float* __restrict__ W,        // [IN_DIM, NCOL]
    float* __restrict__ out_mean,       // [BATCH, HID]
    float* __restrict__ out_new)        // [BATCH, NCOL]
{
    // 4 planes of [128 rows][64 k] bf16: A_hi, A_lo, B_hi, B_lo. 64 KiB.
    __shared__ ushort lds[4 * BM * BK];
    char* const sA_hi = (char*)lds;
    char* const sA_lo = sA_hi + 16384;
    char* const sB_hi = sA_hi + 32768;
    char* const sB_lo = sA_hi + 49152;

    const int t    = threadIdx.x;
    const int lane = t & 63;
    const int wid  = t >> 6;
    const int wr   = wid >> 1;          // wave row 0..1 (64 rows each)
    const int wc   = wid & 1;           // wave col 0..1 (64 cols each)
    const int row0 = blockIdx.x * BM;   // batch tile origin
    const int col0 = blockIdx.y * BN;   // n tile origin

    const int lquad = lane >> 4;        // 0..3
    const int l16   = lane & 15;

    f32x4 acc[4][4] = {};               // 16 fragments of 16x16

    for (int kt = 0; kt < IN_DIM / BK; ++kt) {
        // ---- stage A (x): [128 rows][64 k], k-contiguous, hi/lo planes ----
        // 2048 float4 / 256 thr = 8 each; 16 float4 per row
        #pragma unroll
        for (int j = 0; j < 8; ++j) {
            int f  = j * 256 + t;
            int r  = f >> 4;
            int k4 = (f & 15) * 4;
            const float4 v = *(const float4*)(&x[(size_t)(row0 + r) * IN_DIM + kt * BK + k4]);
            ushort h0 = f2bf(v.x), h1 = f2bf(v.y), h2 = f2bf(v.z), h3 = f2bf(v.w);
            ushort l0 = f2bf(v.x - bf2f(h0));
            ushort l1 = f2bf(v.y - bf2f(h1));
            ushort l2 = f2bf(v.z - bf2f(h2));
            ushort l3 = f2bf(v.w - bf2f(h3));
            int off = swz(r, r * 128 + k4 * 2);
            *(ushort4*)(sA_hi + off) = ushort4{h0, h1, h2, h3};
            *(ushort4*)(sA_lo + off) = ushort4{l0, l1, l2, l3};
        }
        // ---- stage B (W): global [k][n] -> LDS [n][k] (transpose scatter) ----
        // 2048 float4; 32 float4 per k-row
        #pragma unroll
        for (int j = 0; j < 8; ++j) {
            int f  = j * 256 + t;
            int kr = f >> 5;
            int n0 = (f & 31) * 4;
            const float4 v = *(const float4*)(&W[(size_t)(kt * BK + kr) * NCOL + col0 + n0]);
            const float vv[4] = {v.x, v.y, v.z, v.w};
            #pragma unroll
            for (int i = 0; i < 4; ++i) {
                int n = n0 + i;
                ushort h = f2bf(vv[i]);
                ushort l = f2bf(vv[i] - bf2f(h));
                int off = swz(n, n * 128 + kr * 2);
                *(ushort*)(sB_hi + off) = h;
                *(ushort*)(sB_lo + off) = l;
            }
        }
        __syncthreads();

        // ---- MFMA: 3 passes (xh*Wh + xl*Wh + xh*Wl) over 2 k-steps of 32 ----
        #pragma unroll
        for (int ks = 0; ks < 2; ++ks) {
            const int kb = (ks * 32 + 8 * lquad) * 2;   // byte offset in k
            bf16x8 aH[4], bH[4], aL[4], bL[4];
            #pragma unroll
            for (int mi = 0; mi < 4; ++mi) {
                int row = wr * 64 + mi * 16 + l16;
                aH[mi] = *(const bf16x8*)(sA_hi + swz(row, row * 128 + kb));
            }
            #pragma unroll
            for (int ni = 0; ni < 4; ++ni) {
                int row = wc * 64 + ni * 16 + l16;
                bH[ni] = *(const bf16x8*)(sB_hi + swz(row, row * 128 + kb));
            }
            #pragma unroll
            for (int mi = 0; mi < 4; ++mi)
                #pragma unroll
                for (int ni = 0; ni < 4; ++ni)
                    acc[mi][ni] = __builtin_amdgcn_mfma_f32_16x16x32_bf16(aH[mi], bH[ni], acc[mi][ni], 0, 0, 0);
            // pass 2: xl * Wh  (bH still live, then dead)
            #pragma unroll
            for (int mi = 0; mi < 4; ++mi) {
                int row = wr * 64 + mi * 16 + l16;
                aL[mi] = *(const bf16x8*)(sA_lo + swz(row, row * 128 + kb));
            }
            #pragma unroll
            for (int mi = 0; mi < 4; ++mi)
                #pragma unroll
                for (int ni = 0; ni < 4; ++ni)
                    acc[mi][ni] = __builtin_amdgcn_mfma_f32_16x16x32_bf16(aL[mi], bH[ni], acc[mi][ni], 0, 0, 0);
            // pass 3: xh * Wl
            #pragma unroll
            for (int ni = 0; ni < 4; ++ni) {
                int row = wc * 64 + ni * 16 + l16;
                bL[ni] = *(const bf16x8*)(sB_lo + swz(row, row * 128 + kb));
            }
            #pragma unroll
            for (int mi = 0; mi < 4; ++mi)
                #pragma unroll
                for (int ni = 0; ni < 4; ++ni)
                    acc[mi][ni] = __builtin_amdgcn_mfma_f32_16x16x32_bf16(aH[mi], bL[ni], acc[mi][ni], 0, 0, 0);
        }
        __syncthreads();
    }

    // ---- fused epilogue: tanh(C + 0.9*h), write new state, s-group mean ----
    // C/D layout (m89-verified): col = lane&15, row = 4*(lane>>4) + reg
    #pragma unroll
    for (int mi = 0; mi < 4; ++mi) {
        #pragma unroll
        for (int ni = 0; ni < 4; ++ni) {
            const int coln = col0 + wc * 64 + ni * 16 + l16;
            const int hidx = coln >> 4;     // one 16-wide s-group per fragment
            #pragma unroll
            for (int r = 0; r < 4; ++r) {
                const int b = row0 + wr * 64 + mi * 16 + 4 * lquad + r;
                const float hv = hq[(size_t)b * NCOL + coln];
                const float v  = tanh_fast(__builtin_fmaf(0.9f, hv, acc[mi][ni][r]));
                out_new[(size_t)b * NCOL + coln] = v;
                float s = v;
                s += __shfl_xor(s, 1);
                s += __shfl_xor(s, 2);
                s += __shfl_xor(s, 4);
                s += __shfl_xor(s, 8);
                if (l16 == 0)
                    out_mean[(size_t)b * HID + hidx] = s * 0.0625f;
            }
        }
    }
}

extern "C" void kernel_launch(void* const* d_in, const int* in_sizes, int n_in,
                              void* d_out, int out_size, void* d_ws, size_t ws_size,
                              hipStream_t stream) {
    const float* x  = (const float*)d_in[0];   // [4096, 256]
    const float* hq = (const float*)d_in[1];   // [4096, 512, 16]
    const float* W  = (const float*)d_in[2];   // [256, 512, 16]

    float* out_mean = (float*)d_out;                          // [4096, 512]
    float* out_new  = (float*)d_out + (size_t)BATCH * HID;    // [4096, 512, 16]

    dim3 grid(BATCH / BM, NCOL / BN);   // (32, 64)
    dim3 block(256);
    mqc_mfma_kernel<<<grid, block, 0, stream>>>(x, hq, W, out_mean, out_new);
}

// Round 3
// 175.076 us; speedup vs baseline: 1.5651x; 1.5651x over previous
//
#include <hip/hip_runtime.h>

// Problem dims (fixed by reference)
#define BATCH  4096
#define IN_DIM 256
#define HID    512
#define NCOL   8192            // HID * STATES

// Tiling: 128x64 block tile, 4 waves stacked on M (32 rows each), B-only LDS
#define BM 128
#define BN 64
#define BK 64

typedef __attribute__((ext_vector_type(8))) short bf16x8;
typedef __attribute__((ext_vector_type(4))) float f32x4;

// pack bf16(f0) into low16, bf16(f1) into high16 (truncation) — 1 v_perm_b32
__device__ __forceinline__ uint pack_hi(float f0, float f1) {
    return __builtin_amdgcn_perm(__builtin_bit_cast(uint, f1),
                                 __builtin_bit_cast(uint, f0), 0x07060302u);
}
__device__ __forceinline__ float hi_part(float f) {
    return __builtin_bit_cast(float, __builtin_bit_cast(uint, f) & 0xFFFF0000u);
}
// XOR swizzle within a 128B [n][k] row: byte ^= slot(n)<<4
__device__ __forceinline__ int swz(int row, int byteoff) {
    return byteoff ^ ((((row & 7) ^ ((row >> 3) & 7))) << 4);
}
__device__ __forceinline__ float tanh_fast(float x) {
    float e = __builtin_amdgcn_exp2f(x * 2.8853900817779268f); // 2*log2(e)
    float r = __builtin_amdgcn_rcpf(e + 1.0f);
    return __builtin_fmaf(-2.0f, r, 1.0f);
}

__global__ __launch_bounds__(256, 4) void mqc_mfma2_kernel(
    const float* __restrict__ x,        // [BATCH, IN_DIM]
    const float* __restrict__ hq,       // [BATCH, NCOL]
    const float* __restrict__ W,        // [IN_DIM, NCOL]
    float* __restrict__ out_mean,       // [BATCH, HID]
    float* __restrict__ out_new)        // [BATCH, NCOL]
{
    // B planes only: [64 n][64 k] bf16, hi + lo. 16 KiB total.
    __shared__ char sB[2 * BN * BK * 2];
    char* const sB_hi = sB;
    char* const sB_lo = sB + BN * BK * 2;

    const int t     = threadIdx.x;
    const int lane  = t & 63;
    const int w     = t >> 6;           // wave 0..3 -> rows w*32..w*32+31
    const int lquad = lane >> 4;        // 0..3
    const int l16   = lane & 15;
    const int row0  = blockIdx.x * BM;
    const int col0  = blockIdx.y * BN;

    // B staging coords: one 4(k)x4(n) f32 block per thread
    const int k0 = (t >> 4) * 4;        // 0..60
    const int n0 = (t & 15) * 4;        // 0..60

    f32x4 acc[2][4] = {};               // [mi][ni] 16x16 fragments

    for (int kt = 0; kt < IN_DIM / BK; ++kt) {
        // ---- A: direct from global (x is small & cache-hot), 8 float4 ----
        float4 ax[2][2][2];             // [mi][ks][half]
        #pragma unroll
        for (int mi = 0; mi < 2; ++mi)
            #pragma unroll
            for (int ks = 0; ks < 2; ++ks) {
                const float* p = &x[(size_t)(row0 + w * 32 + mi * 16 + l16) * IN_DIM
                                    + kt * BK + ks * 32 + lquad * 8];
                ax[mi][ks][0] = *(const float4*)(p);
                ax[mi][ks][1] = *(const float4*)(p + 4);
            }

        // ---- B stage: 4x4 block, split hi/lo, transpose to [n][k], b64 writes ----
        float4 wrow[4];
        #pragma unroll
        for (int r = 0; r < 4; ++r)
            wrow[r] = *(const float4*)(&W[(size_t)(kt * BK + k0 + r) * NCOL + col0 + n0]);
        #pragma unroll
        for (int c = 0; c < 4; ++c) {
            const float f0 = ((const float*)&wrow[0])[c];
            const float f1 = ((const float*)&wrow[1])[c];
            const float f2 = ((const float*)&wrow[2])[c];
            const float f3 = ((const float*)&wrow[3])[c];
            uint2 hv, lv;
            hv.x = pack_hi(f0, f1);
            hv.y = pack_hi(f2, f3);
            lv.x = pack_hi(f0 - hi_part(f0), f1 - hi_part(f1));
            lv.y = pack_hi(f2 - hi_part(f2), f3 - hi_part(f3));
            const int off = swz(n0 + c, (n0 + c) * (BK * 2) + k0 * 2);
            *(uint2*)(sB_hi + off) = hv;
            *(uint2*)(sB_lo + off) = lv;
        }
        __syncthreads();

        // ---- 3-pass MFMA over 2 k-steps of 32 ----
        #pragma unroll
        for (int ks = 0; ks < 2; ++ks) {
            // convert A regs -> hi/lo bf16 fragments
            bf16x8 aH[2], aL[2];
            #pragma unroll
            for (int mi = 0; mi < 2; ++mi) {
                const float* f = (const float*)&ax[mi][ks][0];
                uint4 h, l;
                h.x = pack_hi(f[0], f[1]); h.y = pack_hi(f[2], f[3]);
                h.z = pack_hi(f[4], f[5]); h.w = pack_hi(f[6], f[7]);
                l.x = pack_hi(f[0] - hi_part(f[0]), f[1] - hi_part(f[1]));
                l.y = pack_hi(f[2] - hi_part(f[2]), f[3] - hi_part(f[3]));
                l.z = pack_hi(f[4] - hi_part(f[4]), f[5] - hi_part(f[5]));
                l.w = pack_hi(f[6] - hi_part(f[6]), f[7] - hi_part(f[7]));
                aH[mi] = __builtin_bit_cast(bf16x8, h);
                aL[mi] = __builtin_bit_cast(bf16x8, l);
            }
            const int kb = ks * 64 + lquad * 16;   // byte offset in k
            bf16x8 bH[4], bL[4];
            #pragma unroll
            for (int ni = 0; ni < 4; ++ni) {
                const int row = ni * 16 + l16;
                bH[ni] = *(const bf16x8*)(sB_hi + swz(row, row * (BK * 2) + kb));
            }
            #pragma unroll
            for (int mi = 0; mi < 2; ++mi)
                #pragma unroll
                for (int ni = 0; ni < 4; ++ni)
                    acc[mi][ni] = __builtin_amdgcn_mfma_f32_16x16x32_bf16(aH[mi], bH[ni], acc[mi][ni], 0, 0, 0);
            #pragma unroll
            for (int mi = 0; mi < 2; ++mi)
                #pragma unroll
                for (int ni = 0; ni < 4; ++ni)
                    acc[mi][ni] = __builtin_amdgcn_mfma_f32_16x16x32_bf16(aL[mi], bH[ni], acc[mi][ni], 0, 0, 0);
            #pragma unroll
            for (int ni = 0; ni < 4; ++ni) {
                const int row = ni * 16 + l16;
                bL[ni] = *(const bf16x8*)(sB_lo + swz(row, row * (BK * 2) + kb));
            }
            #pragma unroll
            for (int mi = 0; mi < 2; ++mi)
                #pragma unroll
                for (int ni = 0; ni < 4; ++ni)
                    acc[mi][ni] = __builtin_amdgcn_mfma_f32_16x16x32_bf16(aH[mi], bL[ni], acc[mi][ni], 0, 0, 0);
        }
        __syncthreads();
    }

    // ---- fused epilogue: tanh(C + 0.9*h), write new state, s-group mean ----
    // C/D layout: col = lane&15, row = 4*(lane>>4) + reg
    #pragma unroll
    for (int mi = 0; mi < 2; ++mi) {
        #pragma unroll
        for (int ni = 0; ni < 4; ++ni) {
            const int coln = col0 + ni * 16 + l16;
            const int hidx = coln >> 4;
            #pragma unroll
            for (int r = 0; r < 4; ++r) {
                const int b = row0 + w * 32 + mi * 16 + 4 * lquad + r;
                const float hv = hq[(size_t)b * NCOL + coln];
                const float v  = tanh_fast(__builtin_fmaf(0.9f, hv, acc[mi][ni][r]));
                out_new[(size_t)b * NCOL + coln] = v;
                float s = v;
                s += __shfl_xor(s, 1);
                s += __shfl_xor(s, 2);
                s += __shfl_xor(s, 4);
                s += __shfl_xor(s, 8);
                if (l16 == 0)
                    out_mean[(size_t)b * HID + hidx] = s * 0.0625f;
            }
        }
    }
}

extern "C" void kernel_launch(void* const* d_in, const int* in_sizes, int n_in,
                              void* d_out, int out_size, void* d_ws, size_t ws_size,
                              hipStream_t stream) {
    const float* x  = (const float*)d_in[0];   // [4096, 256]
    const float* hq = (const float*)d_in[1];   // [4096, 512, 16]
    const float* W  = (const float*)d_in[2];   // [256, 512, 16]

    float* out_mean = (float*)d_out;                          // [4096, 512]
    float* out_new  = (float*)d_out + (size_t)BATCH * HID;    // [4096, 512, 16]

    dim3 grid(BATCH / BM, NCOL / BN);   // (32, 128)
    dim3 block(256);
    mqc_mfma2_kernel<<<grid, block, 0, stream>>>(x, hq, W, out_mean, out_new);
}